// Round 8
// baseline (595.969 us; speedup 1.0000x reference)
//
#include <hip/hip_runtime.h>
#include <hip/hip_cooperative_groups.h>
#include <math.h>

namespace cg = cooperative_groups;

#define UNITS 64
#define TT 100
#define NB 16          // batch rows per workgroup = one MFMA M-tile
#define NTH 256        // 4 waves; wave w owns unit-columns [16w,16w+16) for all 4 gates
#define HSTR 72        // hbuf row stride in halves
#define XQSTR 18       // xt quad stride per timestep (16 rows + 2 pad -> conflict-free)

typedef _Float16 half8 __attribute__((ext_vector_type(8)));
typedef _Float16 half4 __attribute__((ext_vector_type(4)));
typedef float floatx4 __attribute__((ext_vector_type(4)));

#define LOG2E 1.44269504088896f

__device__ __forceinline__ float rcp_fast(float x) { return __builtin_amdgcn_rcpf(x); }
__device__ __forceinline__ float exp2_fast(float x) { return __builtin_amdgcn_exp2f(x); }

__device__ __forceinline__ float fast_sigmoid(float x) {
    return rcp_fast(1.0f + exp2_fast(-LOG2E * x));      // saturates correctly
}
__device__ __forceinline__ float fast_tanh(float x) {
    return __builtin_fmaf(2.0f, rcp_fast(1.0f + exp2_fast(-2.0f * LOG2E * x)), -1.0f);
}

// ---- fallback prologue kernels (used only if cooperative launch fails) ----
__global__ __launch_bounds__(256) void len_kernel(
    const float* __restrict__ x, int* __restrict__ len, int B)
{
    const int row = blockIdx.x * 4 + (threadIdx.x >> 6);
    const int l = threadIdx.x & 63;
    if (row >= B) return;
    const float* xp = x + (size_t)row * (TT * 3);
    int m = 0;
    for (int t = l; t < TT; t += 64) {
        const float a = xp[3*t], b = xp[3*t+1], c = xp[3*t+2];
        if (a != 0.0f || b != 0.0f || c != 0.0f) m = t + 1;
    }
    #pragma unroll
    for (int off = 32; off; off >>= 1) m = max(m, __shfl_down(m, off, 64));
    if (l == 0) len[row] = m;
}

__global__ __launch_bounds__(256) void sort_kernel(
    const int* __restrict__ len, int* __restrict__ perm, int* __restrict__ rlen, int B)
{
    __shared__ int sh_hist[TT + 1];
    __shared__ int sh_base[TT + 1];
    const int tid = threadIdx.x;
    for (int i = tid; i <= TT; i += 256) sh_hist[i] = 0;
    __syncthreads();
    for (int b = tid; b < B; b += 256) atomicAdd(&sh_hist[len[b]], 1);
    __syncthreads();
    if (tid <= TT) {
        int s = 0;
        for (int k = tid + 1; k <= TT; ++k) s += sh_hist[k];
        sh_base[tid] = s;
    }
    __syncthreads();
    for (int b = tid; b < B; b += 256) {
        const int l = len[b];
        const int r = sh_base[l] + atomicAdd(&sh_hist[l], -1) - 1;
        if (r >= 0 && r < B) { perm[r] = b; rlen[r] = l; }
    }
}

__global__ __launch_bounds__(NTH, 4) void lstm_coop_kernel(
    const float* __restrict__ x,    // (B,100,3)
    const float* __restrict__ W,    // (3,256)
    const float* __restrict__ U,    // (64,256)
    const float* __restrict__ bias, // (256,)
    const float* __restrict__ W1,   // (64,64)
    const float* __restrict__ b1,   // (64,)
    const float* __restrict__ W2,   // (64,5)
    const float* __restrict__ b2,   // (5,)
    int* __restrict__ len, int* __restrict__ perm, int* __restrict__ rlen,
    int* __restrict__ hist, int* __restrict__ cursor, int* __restrict__ offs,
    float* __restrict__ out, int B, int do_sort)
{
    __shared__ __align__(16) _Float16 hb[2][NB * HSTR];   // double-buffered h (f16)
    __shared__ __align__(16) _Float16 xt[TT * XQSTR * 4]; // staged x tile: quad {x0,x1,x2,1}
    __shared__ __align__(16) _Float16 zq[8];              // zero quad for q!=0 AX reads
    __shared__ int shInt[128];                            // gb rows / rowlen / (block0) shist
    __shared__ float h1buf[NB * 64];
    __shared__ float logitbuf[NB * 5];

    cg::grid_group grid = cg::this_grid();

    const int tid = threadIdx.x;
    const int w   = tid >> 6;
    const int l   = tid & 63;
    const int q   = l >> 4;
    const int cnl = l & 15;
    const int bi  = blockIdx.x;
    const int b0  = bi * NB;
    const int grp = tid >> 4;   // 0..15: row within tile
    const int sub = tid & 15;

    if (do_sort) {
        // ===== P0: per-row length + zero hist/cursor =====
        {
            const float* xp = x + (size_t)(b0 + grp) * (TT * 3);
            int m = 0;
            for (int t = sub; t < TT; t += 16) {
                const float a = xp[3*t], b = xp[3*t+1], c = xp[3*t+2];
                if (a != 0.0f || b != 0.0f || c != 0.0f) m = t + 1;
            }
            #pragma unroll
            for (int off = 8; off; off >>= 1) m = max(m, __shfl_down(m, off, 16));
            if (sub == 0) len[b0 + grp] = m;
        }
        if (bi == 0 && tid < 101) { hist[tid] = 0; cursor[tid] = 0; }
        grid.sync();
        // ===== P1: histogram =====
        if (tid < NB) atomicAdd(&hist[len[b0 + tid]], 1);
        grid.sync();
        // ===== P2: descending offsets (block 0) =====
        if (bi == 0) {
            if (tid < 101) shInt[tid] = hist[tid];
            __syncthreads();
            if (tid < 101) {
                int s = 0;
                for (int k = tid + 1; k <= TT; ++k) s += shInt[k];
                offs[tid] = s;
            }
        }
        grid.sync();
        // ===== P3: scatter permutation =====
        if (tid < NB) {
            const int b = b0 + tid;
            const int ll = len[b];
            const int r = offs[ll] + atomicAdd(&cursor[ll], 1);
            if (r >= 0 && r < B) { perm[r] = b; rlen[r] = ll; }
        }
        grid.sync();
    }

    // ===== P4: LSTM on ranks [b0, b0+16) =====
    __syncthreads();  // shInt reuse hazard (block 0 used it in P2)
    if (tid < NB) {
        int g = perm ? perm[b0 + tid] : (b0 + tid);
        g = (g < 0) ? 0 : ((g >= B) ? (B - 1) : g);
        shInt[tid] = g;                                    // gb rows
        int ll = rlen ? rlen[b0 + tid] : TT;
        shInt[NB + tid] = (ll < 0) ? 0 : ((ll > TT) ? TT : ll);
    }
    if (tid < 8) zq[tid] = (_Float16)0.0f;
    for (int i = tid; i < NB * HSTR; i += NTH) hb[0][i] = (_Float16)0.0f;
    __syncthreads();  // *** round-7 bug fix: shInt writes visible BEFORE any reader ***

    int maxlen = shInt[NB];               // descending sort -> row 0 is tile max
    maxlen = (maxlen < 0) ? 0 : ((maxlen > TT) ? TT : maxlen);
    int rl[4];
    #pragma unroll
    for (int r = 0; r < 4; ++r) rl[r] = shInt[NB + 4*q + r];

    // ---- stage x tile: row grp, steps sub..maxlen step 16 ----
    {
        const float* xp = x + (size_t)shInt[grp] * (TT * 3);
        for (int t = sub; t < maxlen; t += 16) {
            const float a = xp[3*t], b = xp[3*t+1], c = xp[3*t+2];
            half4 v = { (_Float16)a, (_Float16)b, (_Float16)c, (_Float16)1.0f };
            *(half4*)&xt[(t * XQSTR + grp) * 4] = v;
        }
    }

    // ---- one-time preload: extended-K B fragments. Rows 0..63=U, 64..66=W,
    // 67=bias, 68..95=0.  B-frag (16x16x32): lane holds B[k=32kb+8q+j][zc].
    half8 Bf[4][3];
    #pragma unroll
    for (int g = 0; g < 4; ++g) {
        const int zc = 64 * g + 16 * w + cnl;
        #pragma unroll
        for (int kb = 0; kb < 3; ++kb)
            #pragma unroll
            for (int j = 0; j < 8; ++j) {
                const int k = 32 * kb + 8 * q + j;
                float v = 0.0f;
                if (k < 64)       v = U[k * 256 + zc];
                else if (k < 67)  v = W[(k - 64) * 256 + zc];
                else if (k == 67) v = bias[zc];
                Bf[g][kb][j] = (_Float16)v;
            }
    }

    float c4[4] = {0.0f, 0.0f, 0.0f, 0.0f};
    _Float16 hcur[4] = {(_Float16)0.0f, (_Float16)0.0f, (_Float16)0.0f, (_Float16)0.0f};
    const floatx4 zero4 = {0.0f, 0.0f, 0.0f, 0.0f};

    __syncthreads();   // staging + hb[0] zero + zq visible

    #pragma unroll 1
    for (int t = 0; t < maxlen; ++t) {
        const _Float16* hbc = hb[t & 1];
        _Float16*       hbn = hb[(t + 1) & 1];

        const half8 A0 = *(const half8*)&hbc[cnl * HSTR + 8 * q];
        const half8 A1 = *(const half8*)&hbc[cnl * HSTR + 32 + 8 * q];
        const _Float16* xaddr = (q == 0) ? &xt[(t * XQSTR + cnl) * 4] : zq;
        const half4 x4 = *(const half4*)xaddr;
        const half8 AX = { x4[0], x4[1], x4[2], x4[3],
                           (_Float16)0.0f, (_Float16)0.0f, (_Float16)0.0f, (_Float16)0.0f };

        floatx4 acc[4];
        #pragma unroll
        for (int g = 0; g < 4; ++g) {
            acc[g] = __builtin_amdgcn_mfma_f32_16x16x32_f16(AX, Bf[g][2], zero4, 0, 0, 0);
            acc[g] = __builtin_amdgcn_mfma_f32_16x16x32_f16(A0, Bf[g][0], acc[g], 0, 0, 0);
            acc[g] = __builtin_amdgcn_mfma_f32_16x16x32_f16(A1, Bf[g][1], acc[g], 0, 0, 0);
        }

        #pragma unroll
        for (int r = 0; r < 4; ++r) {
            const bool live = (t < rl[r]);   // mask == (t < len): interior all-zero x has measure 0
            const float iv = fast_sigmoid(acc[0][r]);
            const float fv = fast_sigmoid(acc[1][r]);
            const float gv = fast_tanh  (acc[2][r]);
            const float ov = fast_sigmoid(acc[3][r]);
            const float cn = fv * c4[r] + iv * gv;
            c4[r] = live ? cn : c4[r];
            const _Float16 hn = (_Float16)(ov * fast_tanh(cn));
            hcur[r] = live ? hn : hcur[r];
            hbn[(4 * q + r) * HSTR + 16 * w + cnl] = hcur[r];
        }
        __syncthreads();   // hbn visible; hbc (== next hbn) safe to overwrite next iter
    }

    const _Float16* hbL = hb[maxlen & 1];

    // ---- epilogue: h1 = relu(h @ W1 + b1) ----
    {
        const int j  = tid & 63;
        const int bb = tid >> 6;
        const float bj = b1[j];
        #pragma unroll
        for (int p = 0; p < NB / 4; ++p) {
            const int b = p * 4 + bb;
            float acc = bj;
            #pragma unroll 8
            for (int k = 0; k < UNITS; ++k)
                acc += (float)hbL[b * HSTR + k] * W1[k * 64 + j];
            h1buf[b * 64 + j] = fmaxf(acc, 0.0f);
        }
    }
    __syncthreads();

    if (tid < NB * 5) {
        const int b = tid / 5, s = tid % 5;
        float acc = b2[s];
        for (int j = 0; j < 64; ++j)
            acc += h1buf[b * 64 + j] * W2[j * 5 + s];
        logitbuf[b * 5 + s] = acc;
    }
    __syncthreads();

    if (tid < NB) {
        const int gb = shInt[tid];
        const float l0 = logitbuf[tid * 5 + 0];
        const float l1 = logitbuf[tid * 5 + 1];
        const float l2 = logitbuf[tid * 5 + 2];
        const float l3 = logitbuf[tid * 5 + 3];
        const float l4 = logitbuf[tid * 5 + 4];
        const float m  = fmaxf(fmaxf(fmaxf(l0, l1), fmaxf(l2, l3)), l4);
        const float e0 = __expf(l0 - m), e1 = __expf(l1 - m), e2 = __expf(l2 - m);
        const float e3 = __expf(l3 - m), e4 = __expf(l4 - m);
        const float rs = 1.0f / (e0 + e1 + e2 + e3 + e4);
        out[(size_t)gb * 5 + 0] = e0 * rs;
        out[(size_t)gb * 5 + 1] = e1 * rs;
        out[(size_t)gb * 5 + 2] = e2 * rs;
        out[(size_t)gb * 5 + 3] = e3 * rs;
        out[(size_t)gb * 5 + 4] = e4 * rs;
    }
}

extern "C" void kernel_launch(void* const* d_in, const int* in_sizes, int n_in,
                              void* d_out, int out_size, void* d_ws, size_t ws_size,
                              hipStream_t stream) {
    const float* x  = (const float*)d_in[0];
    const float* W  = (const float*)d_in[1];
    const float* U  = (const float*)d_in[2];
    const float* b  = (const float*)d_in[3];
    const float* W1 = (const float*)d_in[4];
    const float* b1 = (const float*)d_in[5];
    const float* W2 = (const float*)d_in[6];
    const float* b2 = (const float*)d_in[7];
    float* out = (float*)d_out;

    int B = in_sizes[0] / (TT * 3);   // 16384

    // workspace (ints): len[B], perm[B], rlen[B], hist[128], cursor[128], offs[128]
    int* len = nullptr; int* perm = nullptr; int* rlen = nullptr;
    int* hist = nullptr; int* cursor = nullptr; int* offs = nullptr;
    const bool have_ws = ws_size >= ((size_t)3 * B + 384) * sizeof(int);
    if (have_ws) {
        len    = (int*)d_ws;
        perm   = len + B;
        rlen   = perm + B;
        hist   = rlen + B;
        cursor = hist + 128;
        offs   = cursor + 128;
    }

    int do_sort = have_ws ? 1 : 0;
    void* args[] = {
        (void*)&x, (void*)&W, (void*)&U, (void*)&b,
        (void*)&W1, (void*)&b1, (void*)&W2, (void*)&b2,
        (void*)&len, (void*)&perm, (void*)&rlen,
        (void*)&hist, (void*)&cursor, (void*)&offs,
        (void*)&out, (void*)&B, (void*)&do_sort
    };
    hipError_t err = hipSuccess;
    if (have_ws) {
        err = hipLaunchCooperativeKernel((const void*)lstm_coop_kernel,
                                         dim3(B / NB), dim3(NTH), args, 0, stream);
    }
    if (!have_ws || err != hipSuccess) {
        // fallback: multi-dispatch prologue + plain launch (do_sort=0 -> no grid.sync)
        int* fperm = nullptr; int* frlen = nullptr;
        if (have_ws) {
            len_kernel<<<dim3((B + 3) / 4), dim3(256), 0, stream>>>(x, len, B);
            sort_kernel<<<dim3(1), dim3(256), 0, stream>>>(len, perm, rlen, B);
            fperm = perm; frlen = rlen;
        }
        lstm_coop_kernel<<<dim3(B / NB), dim3(NTH), 0, stream>>>(
            x, W, U, b, W1, b1, W2, b2,
            nullptr, fperm, frlen, nullptr, nullptr, nullptr, out, B, 0);
    }
}

// Round 9
// 240.372 us; speedup vs baseline: 2.4794x; 2.4794x over previous
//
#include <hip/hip_runtime.h>
#include <math.h>

#define UNITS 64
#define TT 100
#define NB 16          // batch rows per workgroup = one MFMA M-tile
#define NTH 256        // 4 waves; wave w owns unit-columns [16w,16w+16) for all 4 gates
#define HSTR 72        // hbuf row stride in halves
#define XQSTR 18       // xt quad stride per timestep (16 rows + 2 pad -> conflict-free)

typedef _Float16 half8 __attribute__((ext_vector_type(8)));
typedef _Float16 half4 __attribute__((ext_vector_type(4)));
typedef float floatx4 __attribute__((ext_vector_type(4)));

#define LOG2E 1.44269504088896f

__device__ __forceinline__ float rcp_fast(float x) { return __builtin_amdgcn_rcpf(x); }
__device__ __forceinline__ float exp2_fast(float x) { return __builtin_amdgcn_exp2f(x); }

__device__ __forceinline__ float fast_sigmoid(float x) {
    return rcp_fast(1.0f + exp2_fast(-LOG2E * x));      // saturates correctly
}
__device__ __forceinline__ float fast_tanh(float x) {
    return __builtin_fmaf(2.0f, rcp_fast(1.0f + exp2_fast(-2.0f * LOG2E * x)), -1.0f);
}

// ---- prologue 1: per-row length + global histogram (one atomic per wave) ----
__global__ __launch_bounds__(256) void len_hist_kernel(
    const float* __restrict__ x, int* __restrict__ len, int* __restrict__ hist, int B)
{
    const int row = blockIdx.x * 4 + (threadIdx.x >> 6);
    const int l = threadIdx.x & 63;
    if (row >= B) return;
    const float* xp = x + (size_t)row * (TT * 3);
    int m = 0;
    for (int t = l; t < TT; t += 64) {               // 12B/lane contiguous -> coalesced
        const float a = xp[3*t], b = xp[3*t+1], c = xp[3*t+2];
        if (a != 0.0f || b != 0.0f || c != 0.0f) m = t + 1;
    }
    #pragma unroll
    for (int off = 32; off; off >>= 1) m = max(m, __shfl_down(m, off, 64));
    if (l == 0) { len[row] = m; atomicAdd(&hist[m], 1); }
}

// ---- prologue 2: fused offsets + scatter (64 blocks, one element/thread) ----
__global__ __launch_bounds__(256) void offs_scatter_kernel(
    const int* __restrict__ len, const int* __restrict__ hist, int* __restrict__ cursor,
    int* __restrict__ perm, int* __restrict__ rlen, int B)
{
    __shared__ int sh_hist[TT + 1];
    __shared__ int sh_base[TT + 1];
    const int tid = threadIdx.x;
    if (tid <= TT) sh_hist[tid] = hist[tid];
    __syncthreads();
    if (tid <= TT) {                   // descending-length group offsets (local, race-free)
        int s = 0;
        for (int k = tid + 1; k <= TT; ++k) s += sh_hist[k];
        sh_base[tid] = s;
    }
    __syncthreads();
    const int b = blockIdx.x * 256 + tid;
    if (b < B) {
        const int l = len[b];
        const int r = sh_base[l] + atomicAdd(&cursor[l], 1);
        if (r >= 0 && r < B) { perm[r] = b; rlen[r] = l; }
    }
}

__global__ __launch_bounds__(NTH, 4) void lstm_kernel(
    const float* __restrict__ x,    // (B,100,3)
    const float* __restrict__ W,    // (3,256)
    const float* __restrict__ U,    // (64,256)
    const float* __restrict__ bias, // (256,)
    const float* __restrict__ W1,   // (64,64)
    const float* __restrict__ b1,   // (64,)
    const float* __restrict__ W2,   // (64,5)
    const float* __restrict__ b2,   // (5,)
    const int* __restrict__ perm,   // (B,) rank -> batch, descending length (may be null)
    const int* __restrict__ rlen,   // (B,) length at rank (may be null)
    float* __restrict__ out, int B)
{
    __shared__ __align__(16) _Float16 hb[2][NB * HSTR];   // double-buffered h (f16)
    __shared__ __align__(16) _Float16 xt[TT * XQSTR * 4]; // staged x tile: quads {x0,x1,x2,1}
    __shared__ __align__(16) _Float16 zq[8];              // zero quad for q!=0 AX reads
    __shared__ int shInt[2 * NB];                         // gb rows / row lengths
    __shared__ float h1buf[NB * 64];
    __shared__ float logitbuf[NB * 5];

    const int tid = threadIdx.x;
    const int w   = tid >> 6;
    const int l   = tid & 63;
    const int q   = l >> 4;
    const int cnl = l & 15;
    const int b0  = blockIdx.x * NB;
    const int grp = tid >> 4;   // 0..15: row within tile (for staging)
    const int sub = tid & 15;

    if (tid < NB) {
        int g = perm ? perm[b0 + tid] : (b0 + tid);
        g = (g < 0) ? 0 : ((g >= B) ? (B - 1) : g);
        shInt[tid] = g;
        int ll = rlen ? rlen[b0 + tid] : TT;
        shInt[NB + tid] = (ll < 0) ? 0 : ((ll > TT) ? TT : ll);
    }
    if (tid < 8) zq[tid] = (_Float16)0.0f;
    for (int i = tid; i < NB * HSTR; i += NTH) hb[0][i] = (_Float16)0.0f;
    __syncthreads();   // shInt writes visible before ANY reader (round-7 lesson)

    int maxlen = shInt[NB];           // descending sort -> row 0 is tile max
    maxlen = (maxlen < 0) ? 0 : ((maxlen > TT) ? TT : maxlen);
    int rl[4];
    #pragma unroll
    for (int r = 0; r < 4; ++r) rl[r] = shInt[NB + 4*q + r];

    // ---- stage x tile as f16 quads {x0,x1,x2,1}: row grp, steps sub..maxlen ----
    {
        const float* xp = x + (size_t)shInt[grp] * (TT * 3);
        for (int t = sub; t < maxlen; t += 16) {
            const float a = xp[3*t], b = xp[3*t+1], c = xp[3*t+2];
            half4 v = { (_Float16)a, (_Float16)b, (_Float16)c, (_Float16)1.0f };
            *(half4*)&xt[(t * XQSTR + grp) * 4] = v;
        }
    }

    // ---- one-time preload: extended-K B fragments. Rows 0..63=U, 64..66=W,
    // 67=bias, 68..95=0.  B-frag (16x16x32): lane holds B[k=32kb+8q+j][zc].
    half8 Bf[4][3];
    #pragma unroll
    for (int g = 0; g < 4; ++g) {
        const int zc = 64 * g + 16 * w + cnl;
        #pragma unroll
        for (int kb = 0; kb < 3; ++kb)
            #pragma unroll
            for (int j = 0; j < 8; ++j) {
                const int k = 32 * kb + 8 * q + j;
                float v = 0.0f;
                if (k < 64)       v = U[k * 256 + zc];
                else if (k < 67)  v = W[(k - 64) * 256 + zc];
                else if (k == 67) v = bias[zc];
                Bf[g][kb][j] = (_Float16)v;
            }
    }

    float c4[4] = {0.0f, 0.0f, 0.0f, 0.0f};
    _Float16 hcur[4] = {(_Float16)0.0f, (_Float16)0.0f, (_Float16)0.0f, (_Float16)0.0f};
    const floatx4 zero4 = {0.0f, 0.0f, 0.0f, 0.0f};

    __syncthreads();   // staging + hb[0] zero + zq visible

    #pragma unroll 1
    for (int t = 0; t < maxlen; ++t) {
        const _Float16* hbc = hb[t & 1];
        _Float16*       hbn = hb[(t + 1) & 1];

        // A fragments: lane holds A[m=cnl][k = 32*kb + 8q + j]
        const half8 A0 = *(const half8*)&hbc[cnl * HSTR + 8 * q];
        const half8 A1 = *(const half8*)&hbc[cnl * HSTR + 32 + 8 * q];
        const _Float16* xaddr = (q == 0) ? &xt[(t * XQSTR + cnl) * 4] : zq;
        const half4 x4 = *(const half4*)xaddr;
        const half8 AX = { x4[0], x4[1], x4[2], x4[3],
                           (_Float16)0.0f, (_Float16)0.0f, (_Float16)0.0f, (_Float16)0.0f };

        floatx4 acc[4];
        #pragma unroll
        for (int g = 0; g < 4; ++g) {
            acc[g] = __builtin_amdgcn_mfma_f32_16x16x32_f16(AX, Bf[g][2], zero4, 0, 0, 0);
            acc[g] = __builtin_amdgcn_mfma_f32_16x16x32_f16(A0, Bf[g][0], acc[g], 0, 0, 0);
            acc[g] = __builtin_amdgcn_mfma_f32_16x16x32_f16(A1, Bf[g][1], acc[g], 0, 0, 0);
        }

        #pragma unroll
        for (int r = 0; r < 4; ++r) {
            const bool live = (t < rl[r]);   // mask == (t < len): interior all-zero x has measure 0
            const float iv = fast_sigmoid(acc[0][r]);
            const float fv = fast_sigmoid(acc[1][r]);
            const float gv = fast_tanh  (acc[2][r]);
            const float ov = fast_sigmoid(acc[3][r]);
            const float cn = fv * c4[r] + iv * gv;
            c4[r] = live ? cn : c4[r];
            const _Float16 hn = (_Float16)(ov * fast_tanh(cn));
            hcur[r] = live ? hn : hcur[r];
            hbn[(4 * q + r) * HSTR + 16 * w + cnl] = hcur[r];
        }
        __syncthreads();   // single barrier: hbn visible; hbc (next hbn) safe to overwrite
    }

    const _Float16* hbL = hb[maxlen & 1];

    // ---- epilogue: h1 = relu(h @ W1 + b1) ----
    {
        const int j  = tid & 63;
        const int bb = tid >> 6;
        const float bj = b1[j];
        #pragma unroll
        for (int p = 0; p < NB / 4; ++p) {
            const int b = p * 4 + bb;
            float acc = bj;
            #pragma unroll 8
            for (int k = 0; k < UNITS; ++k)
                acc += (float)hbL[b * HSTR + k] * W1[k * 64 + j];
            h1buf[b * 64 + j] = fmaxf(acc, 0.0f);
        }
    }
    __syncthreads();

    if (tid < NB * 5) {
        const int b = tid / 5, s = tid % 5;
        float acc = b2[s];
        for (int j = 0; j < 64; ++j)
            acc += h1buf[b * 64 + j] * W2[j * 5 + s];
        logitbuf[b * 5 + s] = acc;
    }
    __syncthreads();

    if (tid < NB) {
        const int gb = shInt[tid];
        const float l0 = logitbuf[tid * 5 + 0];
        const float l1 = logitbuf[tid * 5 + 1];
        const float l2 = logitbuf[tid * 5 + 2];
        const float l3 = logitbuf[tid * 5 + 3];
        const float l4 = logitbuf[tid * 5 + 4];
        const float m  = fmaxf(fmaxf(fmaxf(l0, l1), fmaxf(l2, l3)), l4);
        const float e0 = __expf(l0 - m), e1 = __expf(l1 - m), e2 = __expf(l2 - m);
        const float e3 = __expf(l3 - m), e4 = __expf(l4 - m);
        const float rs = 1.0f / (e0 + e1 + e2 + e3 + e4);
        out[(size_t)gb * 5 + 0] = e0 * rs;
        out[(size_t)gb * 5 + 1] = e1 * rs;
        out[(size_t)gb * 5 + 2] = e2 * rs;
        out[(size_t)gb * 5 + 3] = e3 * rs;
        out[(size_t)gb * 5 + 4] = e4 * rs;
    }
}

extern "C" void kernel_launch(void* const* d_in, const int* in_sizes, int n_in,
                              void* d_out, int out_size, void* d_ws, size_t ws_size,
                              hipStream_t stream) {
    const float* x  = (const float*)d_in[0];
    const float* W  = (const float*)d_in[1];
    const float* U  = (const float*)d_in[2];
    const float* b  = (const float*)d_in[3];
    const float* W1 = (const float*)d_in[4];
    const float* b1 = (const float*)d_in[5];
    const float* W2 = (const float*)d_in[6];
    const float* b2 = (const float*)d_in[7];
    float* out = (float*)d_out;

    const int B = in_sizes[0] / (TT * 3);   // 16384

    // workspace (ints): len[B], perm[B], rlen[B], hist[128], cursor[128]
    int* perm = nullptr; int* rlen = nullptr;
    const bool have_ws = ws_size >= ((size_t)3 * B + 256) * sizeof(int);
    if (have_ws) {
        int* len    = (int*)d_ws;
        perm        = len + B;
        rlen        = perm + B;
        int* hist   = rlen + B;
        int* cursor = hist + 128;

        hipMemsetAsync(hist, 0, 256 * sizeof(int), stream);   // hist + cursor
        len_hist_kernel<<<dim3((B + 3) / 4), dim3(256), 0, stream>>>(x, len, hist, B);
        offs_scatter_kernel<<<dim3((B + 255) / 256), dim3(256), 0, stream>>>(
            len, hist, cursor, perm, rlen, B);
    }

    lstm_kernel<<<dim3(B / NB), dim3(NTH), 0, stream>>>(
        x, W, U, b, W1, b1, W2, b2, perm, rlen, out, B);
}